// Round 17
// baseline (77.148 us; speedup 1.0000x reference)
//
#include <hip/hip_runtime.h>
#include <hip/hip_bf16.h>
#include <hip/hip_fp16.h>

#define C 128        // C_IN == C_OUT == 128
#define NCH 32768    // nodes per LDS chunk (2^15), u8-packed counters -> 32 KiB LDS
#define CN 2         // chunks: 2*32768 = 65536 >= n (50000)
#define CNODES (CN * NCH)
#define BE 64        // edge chunks per side

typedef _Float16 f16x8 __attribute__((ext_vector_type(8)));
typedef _Float16 f16x4 __attribute__((ext_vector_type(4)));
typedef float f32x4 __attribute__((ext_vector_type(4)));

// ============================================================================
// Dispatch 1: blocks [0, 2*CN*BE): LDS-privatized u8 histograms;
//             block 2*CN*BE: zero z dummy rows + gbase reset (tiny init).
// ============================================================================
__global__ __launch_bounds__(256) void k_hist(
        const int* __restrict__ row, const int* __restrict__ col,
        unsigned char* __restrict__ part_row, unsigned char* __restrict__ part_col,
        unsigned char* __restrict__ tag, int E,
        __half* __restrict__ Z16, unsigned* __restrict__ gbase, int n) {
    __shared__ unsigned lh[NCH / 4];   // 8192 words = 32 KiB
    int bid = blockIdx.x;
    int tid = threadIdx.x;
    if (bid >= 2 * CN * BE) {
        if (tid < 16) {                // zero dummy row n in both passes
            int pass = tid >> 3, g = tid & 7;
            ((uint4*)(Z16 + ((size_t)pass * (n + 1) + n) * 64))[g] =
                make_uint4(0u, 0u, 0u, 0u);
        }
        if (tid == 16) *gbase = 0u;    // reset scan base counter
        return;
    }
    int side = (bid >= CN * BE) ? 1 : 0;
    int lb = side ? bid - CN * BE : bid;
    int c = lb >> 6;          // / BE  (0..CN-1)
    int b = lb & (BE - 1);
    for (int i = tid * 4; i < NCH / 4; i += 1024) {
        lh[i] = 0u; lh[i + 1] = 0u; lh[i + 2] = 0u; lh[i + 3] = 0u;
    }
    __syncthreads();
    int EPB = (E + BE - 1) / BE;
    int base = b * EPB;
    int end = min(base + EPB, E);
    const int* src = side ? col : row;

#define PROC_ROW(rv, ev)                                                  \
    if (((unsigned)(rv) >> 15) == (unsigned)c) {                          \
        int loc = (rv) & (NCH - 1);                                       \
        unsigned sh = ((unsigned)loc & 3u) << 3;                          \
        unsigned old = atomicAdd(&lh[loc >> 2], 1u << sh);                \
        tag[ev] = (unsigned char)((old >> sh) & 0xffu);                   \
    }
#define PROC_COL(rv)                                                      \
    if (((unsigned)(rv) >> 15) == (unsigned)c) {                          \
        int loc = (rv) & (NCH - 1);                                       \
        atomicAdd(&lh[loc >> 2], 1u << (((unsigned)loc & 3u) << 3));      \
    }
    int nv = 0;
    if ((((uintptr_t)(src + base)) & 15) == 0) nv = (end - base) >> 2;
    const int4* src4 = (const int4*)(src + base);
    if (!side) {
        for (int it = tid; it < nv; it += 256) {
            int4 v = src4[it];
            int e0 = base + it * 4;
            PROC_ROW(v.x, e0);
            PROC_ROW(v.y, e0 + 1);
            PROC_ROW(v.z, e0 + 2);
            PROC_ROW(v.w, e0 + 3);
        }
        for (int e = base + nv * 4 + tid; e < end; e += 256) {
            int r = src[e];
            PROC_ROW(r, e);
        }
    } else {
        for (int it = tid; it < nv; it += 256) {
            int4 v = src4[it];
            PROC_COL(v.x);
            PROC_COL(v.y);
            PROC_COL(v.z);
            PROC_COL(v.w);
        }
        for (int e = base + nv * 4 + tid; e < end; e += 256) {
            int r = src[e];
            PROC_COL(r);
        }
    }
#undef PROC_ROW
#undef PROC_COL
    __syncthreads();
    unsigned* dst = (unsigned*)((side ? part_col : part_row) + (size_t)b * CNODES + c * NCH);
    for (int i = tid; i < NCH / 4; i += 256) dst[i] = lh[i];
}

// ============================================================================
// k_reduce_scan (single-pass): per-node row total + in-place exclusive u8
// offsets; dis; block-scan of PADDED counts; block base via atomicAdd(gbase);
// writes final start/pcnt AND fills this node's pad slots with dummy 'n'.
// ============================================================================
__global__ __launch_bounds__(256) void k_reduce_scan(
        unsigned char* __restrict__ part_row, const unsigned char* __restrict__ part_col,
        unsigned* __restrict__ start, unsigned* __restrict__ pcnt,
        unsigned* __restrict__ gbase, float* __restrict__ dis,
        int* __restrict__ scol, int n) {
    __shared__ unsigned s[256];
    __shared__ unsigned base_sh;
    int t = threadIdx.x;
    int i = blockIdx.x * 256 + t;
    unsigned acc = 0;
    if (i < n) {
#pragma unroll 8
        for (int b = 0; b < BE; ++b) {
            size_t off = (size_t)b * CNODES + i;
            unsigned v = part_row[off];
            part_row[off] = (unsigned char)acc;
            acc += v;
        }
        unsigned d = 0;
#pragma unroll 8
        for (int b = 0; b < BE; ++b) d += part_col[(size_t)b * CNODES + i];
        dis[i] = rsqrtf((float)(d + 1u));
    }
    unsigned v = (i < n) ? ((acc + 15u) & ~15u) : 0u;   // padded count
    s[t] = v;
    __syncthreads();
    for (int off = 1; off < 256; off <<= 1) {
        unsigned add = (t >= off) ? s[t - off] : 0u;
        __syncthreads();
        s[t] += add;
        __syncthreads();
    }
    if (t == 255) base_sh = atomicAdd(gbase, s[255]);
    __syncthreads();
    if (i < n) {
        unsigned sb = base_sh + s[t] - v;   // final exclusive base
        start[i] = sb;
        pcnt[i] = v;
        for (unsigned k = acc; k < v; ++k) scol[sb + k] = n;  // pad dummies
    }
}

// ============================================================================
// Fused: blocks [0,SB): atomic-free scatter (into padded segments);
//        [SB,SB+GB): MFMA GEMM (64 rows/block for occupancy), dis pre-scale,
//        output in 2-pass layout: Z16[pass][m][64ch], fp16.
// ============================================================================
__global__ __launch_bounds__(256) void k_scatter_gemm(
        const int* __restrict__ row, const int* __restrict__ col,
        const unsigned char* __restrict__ tag, const unsigned char* __restrict__ boff,
        const unsigned* __restrict__ start, int* __restrict__ scol, int E, int SB,
        const float* __restrict__ A, const float* __restrict__ W,
        const float* __restrict__ dis, __half* __restrict__ Z16, int n) {
    __shared__ char lds[128 * 256];  // 32 KiB: W stage, then output stage
    int bid = blockIdx.x;
    int tid = threadIdx.x;
    if (bid < SB) {
        int e = bid * 256 + tid;
        if (e < E) {
            int EPB = (E + BE - 1) / BE;
            unsigned b = (unsigned)e / (unsigned)EPB;
            int r = row[e];
            unsigned p = start[r] + boff[(size_t)b * CNODES + r] + tag[e];
            scol[p] = col[e];
        }
        return;
    }
    // ---------------- GEMM: 64 rows per block ----------------
    int w = tid >> 6, lane = tid & 63;
    int m0 = (bid - SB) * 64;

#pragma unroll
    for (int i = 0; i < 16; ++i) {
        int fidx = i * 256 + tid;
        int nr = fidx >> 5;
        int c4 = fidx & 31;
        float4 wv = *(const float4*)(W + (size_t)nr * C + c4 * 4);
        f16x4 hh = {(_Float16)wv.x, (_Float16)wv.y, (_Float16)wv.z, (_Float16)wv.w};
        unsigned byte = (unsigned)(nr * 256 + c4 * 8);
        byte ^= (unsigned)((nr & 7) << 4);
        *(f16x4*)(lds + byte) = hh;
    }
    __syncthreads();

    int q = lane >> 4, rl = lane & 15;
    int r = m0 + w * 16 + rl;               // wave owns 16 rows
    float dm = (r < n) ? dis[r] : 0.f;
    f32x4 acc[8] = {};
#pragma unroll
    for (int kc = 0; kc < 4; ++kc) {
        f16x8 af;
        float4 x0 = make_float4(0.f, 0.f, 0.f, 0.f), x1 = x0;
        if (r < n) {
            const float* srcx = A + (size_t)r * C + kc * 32 + q * 8;
            x0 = *(const float4*)srcx;
            x1 = *(const float4*)(srcx + 4);
        }
        af[0] = (_Float16)(x0.x * dm);
        af[1] = (_Float16)(x0.y * dm);
        af[2] = (_Float16)(x0.z * dm);
        af[3] = (_Float16)(x0.w * dm);
        af[4] = (_Float16)(x1.x * dm);
        af[5] = (_Float16)(x1.y * dm);
        af[6] = (_Float16)(x1.z * dm);
        af[7] = (_Float16)(x1.w * dm);
#pragma unroll
        for (int nt = 0; nt < 8; ++nt) {
            int nrow = nt * 16 + rl;
            unsigned byte = (unsigned)(nrow * 256 + kc * 64 + q * 16);
            byte ^= (unsigned)((nrow & 7) << 4);
            f16x8 bf = *(f16x8*)(lds + byte);
            acc[nt] = __builtin_amdgcn_mfma_f32_16x16x32_f16(af, bf, acc[nt], 0, 0, 0);
        }
    }
    __syncthreads();   // W reads done; reuse LDS for output staging (16 KB)

#pragma unroll
    for (int nt = 0; nt < 8; ++nt)
#pragma unroll
        for (int i = 0; i < 4; ++i) {
            int row_l = w * 16 + q * 4 + i;       // 0..63
            int colh = nt * 16 + rl;
            unsigned byte = (unsigned)(row_l * 256 + colh * 2);
            byte ^= (unsigned)((row_l & 7) << 4);
            *(_Float16*)(lds + byte) = (_Float16)acc[nt][i];
        }
    __syncthreads();

#pragma unroll
    for (int it = 0; it < 4; ++it) {
        int idx = it * 256 + tid;                 // 1024 uint4 total
        int row_l = idx >> 4, c8 = idx & 15;
        unsigned byte = (unsigned)(row_l * 256 + c8 * 16);
        byte ^= (unsigned)((row_l & 7) << 4);
        uint4 v = *(uint4*)(lds + byte);
        int gr = m0 + row_l;
        if (gr < n) {
            int pass = c8 >> 3;        // channel half
            int g = c8 & 7;            // 16 B group within half-row
            *(uint4*)(Z16 + ((size_t)pass * (n + 1) + gr) * 64 + g * 8) = v;
        }
    }
}

// ============================================================================
// k_agg v5 (round-16, proven): 2 channel passes (128 B rows, 6.4 MB/pass).
// Wave = 2 rows x (4 edge-slots x 8 lanes); lane loads uint4; 16-edge batches.
// ============================================================================
__device__ __forceinline__ void add8(uint4 v, float2& a0, float2& a1,
                                     float2& a2, float2& a3) {
    float2 f;
    f = __half22float2(*(__half2*)&v.x); a0.x += f.x; a0.y += f.y;
    f = __half22float2(*(__half2*)&v.y); a1.x += f.x; a1.y += f.y;
    f = __half22float2(*(__half2*)&v.z); a2.x += f.x; a2.y += f.y;
    f = __half22float2(*(__half2*)&v.w); a3.x += f.x; a3.y += f.y;
}

__global__ __launch_bounds__(256) void k_agg(const __half* __restrict__ Z16,
                                             const int* __restrict__ scol,
                                             const unsigned* __restrict__ start,
                                             const unsigned* __restrict__ pcnt,
                                             const float* __restrict__ dis,
                                             const float* __restrict__ bias,
                                             float* __restrict__ out, int n, int RPB) {
    int bid = blockIdx.x;
    int pass = (bid >= RPB) ? 1 : 0;
    int rb = bid - pass * RPB;
    int wid = threadIdx.x >> 6;
    int lane = threadIdx.x & 63;
    int rw = lane >> 5;            // row within the wave's pair
    int slot = (lane >> 3) & 3;    // 0..3 edge slot
    int g = lane & 7;              // 16 B group within 128 B half-row
    int r = rb * 8 + wid * 2 + rw;
    if (r >= n) return;
    unsigned s0 = start[r];
    unsigned s1 = s0 + pcnt[r];    // multiple of 16
    float dr = dis[r];
    const uint4* Z4 = (const uint4*)(Z16 + (size_t)pass * (n + 1) * 64);  // 8 uint4/row
    float2 a0 = {0.f, 0.f}, a1 = a0, a2 = a0, a3 = a0;
    if (slot == 0) {
        uint4 v = Z4[(size_t)r * 8 + g];   // self term
        add8(v, a0, a1, a2, a3);
    }
    for (unsigned k = s0; k < s1; k += 16) {
        int c0 = scol[k + slot];
        int c1 = scol[k + 4 + slot];
        int c2 = scol[k + 8 + slot];
        int c3 = scol[k + 12 + slot];
        uint4 v0 = Z4[(size_t)c0 * 8 + g];
        uint4 v1 = Z4[(size_t)c1 * 8 + g];
        uint4 v2 = Z4[(size_t)c2 * 8 + g];
        uint4 v3 = Z4[(size_t)c3 * 8 + g];
        add8(v0, a0, a1, a2, a3);
        add8(v1, a0, a1, a2, a3);
        add8(v2, a0, a1, a2, a3);
        add8(v3, a0, a1, a2, a3);
    }
    a0.x += __shfl_xor(a0.x, 8);  a0.y += __shfl_xor(a0.y, 8);
    a1.x += __shfl_xor(a1.x, 8);  a1.y += __shfl_xor(a1.y, 8);
    a2.x += __shfl_xor(a2.x, 8);  a2.y += __shfl_xor(a2.y, 8);
    a3.x += __shfl_xor(a3.x, 8);  a3.y += __shfl_xor(a3.y, 8);
    a0.x += __shfl_xor(a0.x, 16); a0.y += __shfl_xor(a0.y, 16);
    a1.x += __shfl_xor(a1.x, 16); a1.y += __shfl_xor(a1.y, 16);
    a2.x += __shfl_xor(a2.x, 16); a2.y += __shfl_xor(a2.y, 16);
    a3.x += __shfl_xor(a3.x, 16); a3.y += __shfl_xor(a3.y, 16);
    if (slot == 0) {
        const float* bp = bias + pass * 64 + g * 8;
        float4 b0 = *(const float4*)bp;
        float4 b1 = *(const float4*)(bp + 4);
        float4 o0, o1;
        o0.x = b0.x + dr * a0.x; o0.y = b0.y + dr * a0.y;
        o0.z = b0.z + dr * a1.x; o0.w = b0.w + dr * a1.y;
        o1.x = b1.x + dr * a2.x; o1.y = b1.y + dr * a2.y;
        o1.z = b1.z + dr * a3.x; o1.w = b1.w + dr * a3.y;
        float* op = out + (size_t)r * C + pass * 64 + g * 8;
        *(float4*)op = o0;
        *(float4*)(op + 4) = o1;
    }
}

extern "C" void kernel_launch(void* const* d_in, const int* in_sizes, int n_in,
                              void* d_out, int out_size, void* d_ws, size_t ws_size,
                              hipStream_t stream) {
    const float* x  = (const float*)d_in[0];
    const int*   ei = (const int*)d_in[1];   // [2, E] flat
    const float* W  = (const float*)d_in[2];
    const float* b  = (const float*)d_in[3];
    float* out = (float*)d_out;

    int n = in_sizes[0] / C;        // 50000 (requires n <= CNODES = 65536)
    int E = in_sizes[1] / 2;        // 800000
    const int* row = ei;
    const int* col = ei + E;

    // workspace layout (512B-aligned slabs), ~30 MB total
    char* p = (char*)d_ws;
    size_t cap  = (size_t)E + 15 * (size_t)n;   // padded scol capacity (1.55M)
    size_t sz_part = (((size_t)BE * CNODES) + 511) & ~(size_t)511;   // 4 MB (u8)
    size_t sz_n    = (((size_t)n * 4) + 511) & ~(size_t)511;
    size_t sz_E1   = (((size_t)E) + 511) & ~(size_t)511;
    size_t sz_cap  = ((cap * 4) + 511) & ~(size_t)511;
    size_t off = 0;
    unsigned char*  part_row = (unsigned char*)(p + off);  off += sz_part;
    unsigned char*  part_col = (unsigned char*)(p + off);  off += sz_part;
    unsigned*       start    = (unsigned*)(p + off);       off += sz_n;
    unsigned*       pcnt     = (unsigned*)(p + off);       off += sz_n;
    float*          dis      = (float*)(p + off);          off += sz_n;
    unsigned*       gbase    = (unsigned*)(p + off);       off += 512;
    unsigned char*  tag      = (unsigned char*)(p + off);  off += sz_E1;
    int*            scol     = (int*)(p + off);            off += sz_cap;
    __half*         z16      = (__half*)(p + off);         // 2*(n+1)*64 halves

    int NT = 256;
    int NB = (n + NT - 1) / NT;     // 196 <= 256
    int SB = (E + NT - 1) / NT;     // 3125
    int GB = (n + 63) / 64;         // 782 gemm blocks (64 rows each)
    int RPB = (n + 7) / 8;          // 6250 row-blocks per pass

    k_hist<<<2 * CN * BE + 1, NT, 0, stream>>>(row, col, part_row, part_col, tag, E,
                                               z16, gbase, n);
    k_reduce_scan<<<NB, NT, 0, stream>>>(part_row, part_col, start, pcnt, gbase, dis,
                                         scol, n);
    k_scatter_gemm<<<SB + GB, NT, 0, stream>>>(row, col, tag, part_row, start, scol,
                                               E, SB, x, W, dis, z16, n);
    k_agg<<<2 * RPB, NT, 0, stream>>>(z16, scol, start, pcnt, dis, b, out, n, RPB);
}

// Round 18
// 76.748 us; speedup vs baseline: 1.0052x; 1.0052x over previous
//
#include <hip/hip_runtime.h>
#include <hip/hip_bf16.h>
#include <hip/hip_fp16.h>

#define C 128        // C_IN == C_OUT == 128
#define NCH 32768    // nodes per LDS chunk (2^15), u8-packed counters -> 32 KiB LDS
#define CN 2         // chunks: 2*32768 = 65536 >= n (50000)
#define CNODES (CN * NCH)
#define BE 128       // edge chunks per side (512 hist blocks = 2/CU)

typedef _Float16 f16x8 __attribute__((ext_vector_type(8)));
typedef _Float16 f16x4 __attribute__((ext_vector_type(4)));
typedef float f32x4 __attribute__((ext_vector_type(4)));

// ============================================================================
// Dispatch 1: blocks [0, 2*CN*BE): LDS-privatized u8 histograms;
//             block 2*CN*BE: zero z dummy rows + gbase reset (tiny init).
// ============================================================================
__global__ __launch_bounds__(256) void k_hist(
        const int* __restrict__ row, const int* __restrict__ col,
        unsigned char* __restrict__ part_row, unsigned char* __restrict__ part_col,
        unsigned char* __restrict__ tag, int E, int EPB,
        __half* __restrict__ Z16, unsigned* __restrict__ gbase, int n) {
    __shared__ unsigned lh[NCH / 4];   // 8192 words = 32 KiB
    int bid = blockIdx.x;
    int tid = threadIdx.x;
    if (bid >= 2 * CN * BE) {
        if (tid < 16) {                // zero dummy row n in both passes
            int pass = tid >> 3, g = tid & 7;
            ((uint4*)(Z16 + ((size_t)pass * (n + 1) + n) * 64))[g] =
                make_uint4(0u, 0u, 0u, 0u);
        }
        if (tid == 16) *gbase = 0u;    // reset scan base counter
        return;
    }
    int side = (bid >= CN * BE) ? 1 : 0;
    int lb = side ? bid - CN * BE : bid;
    int c = lb >> 7;          // / BE  (0..CN-1)
    int b = lb & (BE - 1);
    for (int i = tid * 4; i < NCH / 4; i += 1024) {
        lh[i] = 0u; lh[i + 1] = 0u; lh[i + 2] = 0u; lh[i + 3] = 0u;
    }
    __syncthreads();
    int base = b * EPB;
    int end = min(base + EPB, E);
    const int* src = side ? col : row;

#define PROC_ROW(rv, ev)                                                  \
    if (((unsigned)(rv) >> 15) == (unsigned)c) {                          \
        int loc = (rv) & (NCH - 1);                                       \
        unsigned sh = ((unsigned)loc & 3u) << 3;                          \
        unsigned old = atomicAdd(&lh[loc >> 2], 1u << sh);                \
        tag[ev] = (unsigned char)((old >> sh) & 0xffu);                   \
    }
#define PROC_COL(rv)                                                      \
    if (((unsigned)(rv) >> 15) == (unsigned)c) {                          \
        int loc = (rv) & (NCH - 1);                                       \
        atomicAdd(&lh[loc >> 2], 1u << (((unsigned)loc & 3u) << 3));      \
    }
    int nv = (end > base) ? ((end - base) >> 2) : 0;   // EPB %4==0 -> aligned
    const int4* src4 = (const int4*)(src + base);
    if (!side) {
        for (int it = tid; it < nv; it += 256) {
            int4 v = src4[it];
            int e0 = base + it * 4;
            PROC_ROW(v.x, e0);
            PROC_ROW(v.y, e0 + 1);
            PROC_ROW(v.z, e0 + 2);
            PROC_ROW(v.w, e0 + 3);
        }
        for (int e = base + nv * 4 + tid; e < end; e += 256) {
            int r = src[e];
            PROC_ROW(r, e);
        }
    } else {
        for (int it = tid; it < nv; it += 256) {
            int4 v = src4[it];
            PROC_COL(v.x);
            PROC_COL(v.y);
            PROC_COL(v.z);
            PROC_COL(v.w);
        }
        for (int e = base + nv * 4 + tid; e < end; e += 256) {
            int r = src[e];
            PROC_COL(r);
        }
    }
#undef PROC_ROW
#undef PROC_COL
    __syncthreads();
    unsigned* dst = (unsigned*)((side ? part_col : part_row) + (size_t)b * CNODES + c * NCH);
    for (int i = tid; i < NCH / 4; i += 256) dst[i] = lh[i];
}

// ============================================================================
// Dispatch 2: blocks [0,NB): single-pass reduce+scan (final start/pcnt, dis,
//             pad-dummy fill); blocks [NB,NB+GB): MFMA GEMM (64 rows/block)
//             computing its own dis inline from part_col (no dep on scan).
// Disjoint writes: scan -> start/pcnt/dis/scol-pads; gemm -> Z16. No race.
// ============================================================================
__global__ __launch_bounds__(256) void k_scan_gemm(
        unsigned char* __restrict__ part_row, const unsigned char* __restrict__ part_col,
        unsigned* __restrict__ start, unsigned* __restrict__ pcnt,
        unsigned* __restrict__ gbase, float* __restrict__ dis,
        int* __restrict__ scol, int NB,
        const float* __restrict__ A, const float* __restrict__ W,
        __half* __restrict__ Z16, int n) {
    __shared__ char lds[128 * 256];  // 32 KiB (gemm); scan aliases first 1.25 KB
    int bid = blockIdx.x;
    int tid = threadIdx.x;

    if (bid < NB) {
        // ---------------- reduce + scan ----------------
        unsigned* s = (unsigned*)lds;
        unsigned* base_sh = (unsigned*)(lds + 1024);
        int t = tid;
        int i = bid * 256 + t;
        unsigned acc = 0;
        if (i < n) {
#pragma unroll 8
            for (int b = 0; b < BE; ++b) {
                size_t off = (size_t)b * CNODES + i;
                unsigned v = part_row[off];
                part_row[off] = (unsigned char)acc;
                acc += v;
            }
            unsigned d = 0;
#pragma unroll 8
            for (int b = 0; b < BE; ++b) d += part_col[(size_t)b * CNODES + i];
            dis[i] = rsqrtf((float)(d + 1u));
        }
        unsigned v = (i < n) ? ((acc + 15u) & ~15u) : 0u;   // padded count
        s[t] = v;
        __syncthreads();
        for (int off = 1; off < 256; off <<= 1) {
            unsigned add = (t >= off) ? s[t - off] : 0u;
            __syncthreads();
            s[t] += add;
            __syncthreads();
        }
        if (t == 255) *base_sh = atomicAdd(gbase, s[255]);
        __syncthreads();
        if (i < n) {
            unsigned sb = *base_sh + s[t] - v;   // final exclusive base
            start[i] = sb;
            pcnt[i] = v;
            for (unsigned k = acc; k < v; ++k) scol[sb + k] = n;  // pad dummies
        }
        return;
    }

    // ---------------- GEMM: 64 rows per block, inline dis ----------------
    int w = tid >> 6, lane = tid & 63;
    int m0 = (bid - NB) * 64;

#pragma unroll
    for (int i = 0; i < 16; ++i) {
        int fidx = i * 256 + tid;
        int nr = fidx >> 5;
        int c4 = fidx & 31;
        float4 wv = *(const float4*)(W + (size_t)nr * C + c4 * 4);
        f16x4 hh = {(_Float16)wv.x, (_Float16)wv.y, (_Float16)wv.z, (_Float16)wv.w};
        unsigned byte = (unsigned)(nr * 256 + c4 * 8);
        byte ^= (unsigned)((nr & 7) << 4);
        *(f16x4*)(lds + byte) = hh;
    }

    int q = lane >> 4, rl = lane & 15;
    int r = m0 + w * 16 + rl;               // wave owns 16 rows; r < 50048 < CNODES
    // inline degree: each q-lane sums BE/4 partials, butterfly over lane bits 4,5
    unsigned d = 0;
#pragma unroll 8
    for (int j = 0; j < BE / 4; ++j)
        d += part_col[(size_t)(q * (BE / 4) + j) * CNODES + r];
    d += (unsigned)__shfl_xor((int)d, 16);
    d += (unsigned)__shfl_xor((int)d, 32);
    float dm = (r < n) ? rsqrtf((float)(d + 1u)) : 0.f;
    __syncthreads();   // W staged

    f32x4 acc[8] = {};
#pragma unroll
    for (int kc = 0; kc < 4; ++kc) {
        f16x8 af;
        float4 x0 = make_float4(0.f, 0.f, 0.f, 0.f), x1 = x0;
        if (r < n) {
            const float* srcx = A + (size_t)r * C + kc * 32 + q * 8;
            x0 = *(const float4*)srcx;
            x1 = *(const float4*)(srcx + 4);
        }
        af[0] = (_Float16)(x0.x * dm);
        af[1] = (_Float16)(x0.y * dm);
        af[2] = (_Float16)(x0.z * dm);
        af[3] = (_Float16)(x0.w * dm);
        af[4] = (_Float16)(x1.x * dm);
        af[5] = (_Float16)(x1.y * dm);
        af[6] = (_Float16)(x1.z * dm);
        af[7] = (_Float16)(x1.w * dm);
#pragma unroll
        for (int nt = 0; nt < 8; ++nt) {
            int nrow = nt * 16 + rl;
            unsigned byte = (unsigned)(nrow * 256 + kc * 64 + q * 16);
            byte ^= (unsigned)((nrow & 7) << 4);
            f16x8 bf = *(f16x8*)(lds + byte);
            acc[nt] = __builtin_amdgcn_mfma_f32_16x16x32_f16(af, bf, acc[nt], 0, 0, 0);
        }
    }
    __syncthreads();   // W reads done; reuse LDS for output staging

#pragma unroll
    for (int nt = 0; nt < 8; ++nt)
#pragma unroll
        for (int i = 0; i < 4; ++i) {
            int row_l = w * 16 + q * 4 + i;       // 0..63
            int colh = nt * 16 + rl;
            unsigned byte = (unsigned)(row_l * 256 + colh * 2);
            byte ^= (unsigned)((row_l & 7) << 4);
            *(_Float16*)(lds + byte) = (_Float16)acc[nt][i];
        }
    __syncthreads();

#pragma unroll
    for (int it = 0; it < 4; ++it) {
        int idx = it * 256 + tid;                 // 1024 uint4 total
        int row_l = idx >> 4, c8 = idx & 15;
        unsigned byte = (unsigned)(row_l * 256 + c8 * 16);
        byte ^= (unsigned)((row_l & 7) << 4);
        uint4 v = *(uint4*)(lds + byte);
        int gr = m0 + row_l;
        if (gr < n) {
            int pass = c8 >> 3;        // channel half
            int g = c8 & 7;            // 16 B group within half-row
            *(uint4*)(Z16 + ((size_t)pass * (n + 1) + gr) * 64 + g * 8) = v;
        }
    }
}

// ============================================================================
// Dispatch 3: atomic-free scatter into padded segments.
// ============================================================================
__global__ __launch_bounds__(256) void k_scatter(
        const int* __restrict__ row, const int* __restrict__ col,
        const unsigned char* __restrict__ tag, const unsigned char* __restrict__ boff,
        const unsigned* __restrict__ start, int* __restrict__ scol, int E, int EPB) {
    int e = blockIdx.x * 256 + threadIdx.x;
    if (e < E) {
        unsigned b = (unsigned)e / (unsigned)EPB;
        int r = row[e];
        unsigned p = start[r] + boff[(size_t)b * CNODES + r] + tag[e];
        scol[p] = col[e];
    }
}

// ============================================================================
// k_agg v5 (round-16, proven): 2 channel passes (128 B rows, 6.4 MB/pass).
// Wave = 2 rows x (4 edge-slots x 8 lanes); lane loads uint4; 16-edge batches.
// ============================================================================
__device__ __forceinline__ void add8(uint4 v, float2& a0, float2& a1,
                                     float2& a2, float2& a3) {
    float2 f;
    f = __half22float2(*(__half2*)&v.x); a0.x += f.x; a0.y += f.y;
    f = __half22float2(*(__half2*)&v.y); a1.x += f.x; a1.y += f.y;
    f = __half22float2(*(__half2*)&v.z); a2.x += f.x; a2.y += f.y;
    f = __half22float2(*(__half2*)&v.w); a3.x += f.x; a3.y += f.y;
}

__global__ __launch_bounds__(256) void k_agg(const __half* __restrict__ Z16,
                                             const int* __restrict__ scol,
                                             const unsigned* __restrict__ start,
                                             const unsigned* __restrict__ pcnt,
                                             const float* __restrict__ dis,
                                             const float* __restrict__ bias,
                                             float* __restrict__ out, int n, int RPB) {
    int bid = blockIdx.x;
    int pass = (bid >= RPB) ? 1 : 0;
    int rb = bid - pass * RPB;
    int wid = threadIdx.x >> 6;
    int lane = threadIdx.x & 63;
    int rw = lane >> 5;            // row within the wave's pair
    int slot = (lane >> 3) & 3;    // 0..3 edge slot
    int g = lane & 7;              // 16 B group within 128 B half-row
    int r = rb * 8 + wid * 2 + rw;
    if (r >= n) return;
    unsigned s0 = start[r];
    unsigned s1 = s0 + pcnt[r];    // multiple of 16
    float dr = dis[r];
    const uint4* Z4 = (const uint4*)(Z16 + (size_t)pass * (n + 1) * 64);  // 8 uint4/row
    float2 a0 = {0.f, 0.f}, a1 = a0, a2 = a0, a3 = a0;
    if (slot == 0) {
        uint4 v = Z4[(size_t)r * 8 + g];   // self term
        add8(v, a0, a1, a2, a3);
    }
    for (unsigned k = s0; k < s1; k += 16) {
        int c0 = scol[k + slot];
        int c1 = scol[k + 4 + slot];
        int c2 = scol[k + 8 + slot];
        int c3 = scol[k + 12 + slot];
        uint4 v0 = Z4[(size_t)c0 * 8 + g];
        uint4 v1 = Z4[(size_t)c1 * 8 + g];
        uint4 v2 = Z4[(size_t)c2 * 8 + g];
        uint4 v3 = Z4[(size_t)c3 * 8 + g];
        add8(v0, a0, a1, a2, a3);
        add8(v1, a0, a1, a2, a3);
        add8(v2, a0, a1, a2, a3);
        add8(v3, a0, a1, a2, a3);
    }
    a0.x += __shfl_xor(a0.x, 8);  a0.y += __shfl_xor(a0.y, 8);
    a1.x += __shfl_xor(a1.x, 8);  a1.y += __shfl_xor(a1.y, 8);
    a2.x += __shfl_xor(a2.x, 8);  a2.y += __shfl_xor(a2.y, 8);
    a3.x += __shfl_xor(a3.x, 8);  a3.y += __shfl_xor(a3.y, 8);
    a0.x += __shfl_xor(a0.x, 16); a0.y += __shfl_xor(a0.y, 16);
    a1.x += __shfl_xor(a1.x, 16); a1.y += __shfl_xor(a1.y, 16);
    a2.x += __shfl_xor(a2.x, 16); a2.y += __shfl_xor(a2.y, 16);
    a3.x += __shfl_xor(a3.x, 16); a3.y += __shfl_xor(a3.y, 16);
    if (slot == 0) {
        const float* bp = bias + pass * 64 + g * 8;
        float4 b0 = *(const float4*)bp;
        float4 b1 = *(const float4*)(bp + 4);
        float4 o0, o1;
        o0.x = b0.x + dr * a0.x; o0.y = b0.y + dr * a0.y;
        o0.z = b0.z + dr * a1.x; o0.w = b0.w + dr * a1.y;
        o1.x = b1.x + dr * a2.x; o1.y = b1.y + dr * a2.y;
        o1.z = b1.z + dr * a3.x; o1.w = b1.w + dr * a3.y;
        float* op = out + (size_t)r * C + pass * 64 + g * 8;
        *(float4*)op = o0;
        *(float4*)(op + 4) = o1;
    }
}

extern "C" void kernel_launch(void* const* d_in, const int* in_sizes, int n_in,
                              void* d_out, int out_size, void* d_ws, size_t ws_size,
                              hipStream_t stream) {
    const float* x  = (const float*)d_in[0];
    const int*   ei = (const int*)d_in[1];   // [2, E] flat
    const float* W  = (const float*)d_in[2];
    const float* b  = (const float*)d_in[3];
    float* out = (float*)d_out;

    int n = in_sizes[0] / C;        // 50000 (requires n <= CNODES = 65536)
    int E = in_sizes[1] / 2;        // 800000
    const int* row = ei;
    const int* col = ei + E;

    // workspace layout (512B-aligned slabs), ~37 MB total
    char* p = (char*)d_ws;
    size_t cap  = (size_t)E + 15 * (size_t)n;   // padded scol capacity (1.55M)
    size_t sz_part = (((size_t)BE * CNODES) + 511) & ~(size_t)511;   // 8 MB (u8)
    size_t sz_n    = (((size_t)n * 4) + 511) & ~(size_t)511;
    size_t sz_E1   = (((size_t)E) + 511) & ~(size_t)511;
    size_t sz_cap  = ((cap * 4) + 511) & ~(size_t)511;
    size_t off = 0;
    unsigned char*  part_row = (unsigned char*)(p + off);  off += sz_part;
    unsigned char*  part_col = (unsigned char*)(p + off);  off += sz_part;
    unsigned*       start    = (unsigned*)(p + off);       off += sz_n;
    unsigned*       pcnt     = (unsigned*)(p + off);       off += sz_n;
    float*          dis      = (float*)(p + off);          off += sz_n;
    unsigned*       gbase    = (unsigned*)(p + off);       off += 512;
    unsigned char*  tag      = (unsigned char*)(p + off);  off += sz_E1;
    int*            scol     = (int*)(p + off);            off += sz_cap;
    __half*         z16      = (__half*)(p + off);         // 2*(n+1)*64 halves

    int NT = 256;
    int NB = (n + NT - 1) / NT;                   // 196 <= 256
    int EPB = (((E + BE - 1) / BE) + 3) & ~3;     // 6252, %4==0 (int4 align)
    int SB = (E + NT - 1) / NT;                   // 3125
    int GB = (n + 63) / 64;                       // 782 gemm blocks (64 rows)
    int RPB = (n + 7) / 8;                        // 6250 row-blocks per pass

    k_hist<<<2 * CN * BE + 1, NT, 0, stream>>>(row, col, part_row, part_col, tag, E,
                                               EPB, z16, gbase, n);
    k_scan_gemm<<<NB + GB, NT, 0, stream>>>(part_row, part_col, start, pcnt, gbase,
                                            dis, scol, NB, x, W, z16, n);
    k_scatter<<<SB, NT, 0, stream>>>(row, col, tag, part_row, start, scol, E, EPB);
    k_agg<<<2 * RPB, NT, 0, stream>>>(z16, scol, start, pcnt, dis, b, out, n, RPB);
}